// Round 3
// baseline (603.534 us; speedup 1.0000x reference)
//
#include <hip/hip_runtime.h>
#include <stdint.h>

typedef unsigned short u16;
typedef __attribute__((ext_vector_type(8))) short short8;
typedef __attribute__((ext_vector_type(4))) float floatx4;

#define BB 16
#define NN1 1024
#define NN2 4096
#define DIM 512
#define M1 (BB*NN1)    // 16384
#define M2 (BB*NN2)    // 65536

__device__ __forceinline__ float bf2f(u16 u){
  union { unsigned int i; float f; } v; v.i = ((unsigned int)u) << 16; return v.f;
}
__device__ __forceinline__ u16 f2bf(float f){
  union { float f; unsigned int i; } v; v.f = f;
  unsigned int i = v.i;
  return (u16)((i + 0x7FFFu + ((i >> 16) & 1u)) >> 16);  // RNE (exact for bf16-quantized)
}

// ---------------- zero stats ----------------
__global__ void zero_stats(float* p){
  p[blockIdx.x * 256 + threadIdx.x] = 0.0f;   // grid 8 -> 2048 floats
}

// ---- weight transpose + f32->bf16: src f32 [K][N] -> dst bf16 [N][K] ----
__global__ void transpose_w(const float* __restrict__ src, u16* __restrict__ dst,
                            int K, int N){
  int idx = blockIdx.x * 256 + threadIdx.x;
  if (idx < K * N){
    int n = idx / K, k = idx % K;
    dst[idx] = f2bf(src[k * N + n]);
  }
}

// ---- MFMA GEMM: Y[M][512] = A_f32[M][K] @ W; BT = bf16 W^T [512][K] ----
// out_is_f32: write f32 (Y2 path) else bf16 (Y1 path). bias is f32.
__global__ __launch_bounds__(256) void gemm_mfma(
    const float* __restrict__ A, const u16* __restrict__ BT,
    const float* __restrict__ bias, void* __restrict__ Yv,
    int M, int K, int out_is_f32)
{
  const int N = 512;
  __shared__ u16 As[128][40];   // +8 pad breaks pow2 bank stride
  __shared__ u16 Bs[128][40];
  int tid  = threadIdx.x;
  int lane = tid & 63, wave = tid >> 6;
  int bn = blockIdx.x, bm = blockIdx.y;   // bn fast: 4 blocks share the A tile via L2
  int wm = (wave & 1) * 64, wn = (wave >> 1) * 64;
  int r16 = lane & 15, quad = lane >> 4;

  floatx4 acc[4][4];
  for (int i = 0; i < 4; i++)
    for (int j = 0; j < 4; j++)
      acc[i][j] = (floatx4)(0.0f);

  int lr = tid >> 2;            // 0..63
  int lc = (tid & 3) * 8;       // 0,8,16,24  (8 consecutive k per thread)

  const float* Ag = A  + (size_t)(bm * 128) * K;
  const u16*   Bg = BT + (size_t)(bn * 128) * K;

  for (int k0 = 0; k0 < K; k0 += 32){
    for (int rr = 0; rr < 2; rr++){
      int row = lr + rr * 64;
      const float* ap = Ag + (size_t)row * K + k0 + lc;
      float4 a0 = *(const float4*)ap;
      float4 a1 = *(const float4*)(ap + 4);
      u16 t[8] = { f2bf(a0.x), f2bf(a0.y), f2bf(a0.z), f2bf(a0.w),
                   f2bf(a1.x), f2bf(a1.y), f2bf(a1.z), f2bf(a1.w) };
      *(uint4*)(&As[row][lc]) = *(const uint4*)t;
      uint4 vb = *(const uint4*)(Bg + (size_t)row * K + k0 + lc);
      *(uint4*)(&Bs[row][lc]) = vb;
    }
    __syncthreads();
    short8 af[4], bfr[4];
    for (int i = 0; i < 4; i++) af[i]  = *(const short8*)(&As[wm + i*16 + r16][quad*8]);
    for (int j = 0; j < 4; j++) bfr[j] = *(const short8*)(&Bs[wn + j*16 + r16][quad*8]);
    for (int i = 0; i < 4; i++)
      for (int j = 0; j < 4; j++)
        acc[i][j] = __builtin_amdgcn_mfma_f32_16x16x32_bf16(af[i], bfr[j], acc[i][j], 0, 0, 0);
    __syncthreads();
  }

  // epilogue: C/D layout col = lane&15, row = quad*4 + reg (m89-verified)
  for (int i = 0; i < 4; i++){
    int rowb = bm * 128 + wm + i * 16 + quad * 4;
    for (int j = 0; j < 4; j++){
      int col = bn * 128 + wn + j * 16 + r16;
      float bv = bias[col];
      for (int r = 0; r < 4; r++){
        float v = acc[i][j][r] + bv;
        size_t idx = (size_t)(rowb + r) * N + col;
        if (out_is_f32) ((float*)Yv)[idx] = v;
        else            ((u16*)Yv)[idx]   = f2bf(v);
      }
    }
  }
}

// ---------------- per-channel sum / sumsq (bf16 source) ----------------
__global__ void colstats_bf16(const u16* __restrict__ Y, float* __restrict__ sum,
                              float* __restrict__ sumsq, int rows_per_block){
  int c  = (blockIdx.x & 1) * 256 + threadIdx.x;
  int r0 = (blockIdx.x >> 1) * rows_per_block;
  float s = 0.0f, q = 0.0f;
  const u16* p = Y + (size_t)r0 * 512 + c;
  for (int r = 0; r < rows_per_block; r++){
    float v = bf2f(p[(size_t)r * 512]);
    s += v; q += v * v;
  }
  atomicAdd(&sum[c], s);
  atomicAdd(&sumsq[c], q);
}

// ---------------- per-channel sum / sumsq (f32 source) ----------------
__global__ void colstats_f32(const float* __restrict__ Y, float* __restrict__ sum,
                             float* __restrict__ sumsq, int rows_per_block){
  int c  = (blockIdx.x & 1) * 256 + threadIdx.x;
  int r0 = (blockIdx.x >> 1) * rows_per_block;
  float s = 0.0f, q = 0.0f;
  const float* p = Y + (size_t)r0 * 512 + c;
  for (int r = 0; r < rows_per_block; r++){
    float v = p[(size_t)r * 512];
    s += v; q += v * v;
  }
  atomicAdd(&sum[c], s);
  atomicAdd(&sumsq[c], q);
}

// ---------------- BN coefficients: a = gamma/sqrt(var+eps), b = beta - mu*a ----------------
__global__ void bn_coeff(const float* __restrict__ stats,
                         const float* __restrict__ g1, const float* __restrict__ be1,
                         const float* __restrict__ g2, const float* __restrict__ be2,
                         float* __restrict__ coef){
  int c = threadIdx.x;  // 512
  {
    float mu  = stats[c] / (float)M1;
    float var = stats[512 + c] / (float)M1 - mu * mu;
    var = fmaxf(var, 0.0f);
    float a = g1[c] * (1.0f / sqrtf(var + 1e-5f));
    coef[c] = a;
    coef[512 + c] = be1[c] - mu * a;
  }
  {
    float mu  = stats[1024 + c] / (float)M2;
    float var = stats[1536 + c] / (float)M2 - mu * mu;
    var = fmaxf(var, 0.0f);
    float a = g2[c] * (1.0f / sqrtf(var + 1e-5f));
    coef[1024 + c] = a;
    coef[1536 + c] = be2[c] - mu * a;
  }
}

// ---------------- xyz2 passthrough (bit-exact f32 copy: 786432 B) ----------------
__global__ void copy_xyz(const uint4* __restrict__ src, uint4* __restrict__ dst){
  int i = blockIdx.x * 256 + threadIdx.x;   // grid 192 -> 49152 * 16B
  dst[i] = src[i];
}

// ---- 3-NN inverse-distance interp FUSED with BN1/BN2+ReLU+add; one wave/query ----
// outF row holds pre-BN Y2 (f32) on entry; on exit it holds the final feats row.
__global__ __launch_bounds__(64) void interp_final(
    const float* __restrict__ xyz1, const float* __restrict__ xyz2,
    const u16* __restrict__ Y1, const float* __restrict__ coef,
    float* __restrict__ outF)
{
  int lane = threadIdx.x;
  int bid  = blockIdx.x;
  int b = bid >> 12;           // /4096

  const float* pd = xyz2 + (size_t)bid * 3;
  double xd = (double)pd[0];
  double yd = (double)pd[1];
  double zd = (double)pd[2];

  // f64 distances (exact for bf16-quantized coords -> true ordering)
  double dl[16];
  const float* ps = xyz1 + (size_t)b * NN1 * 3;
  for (int s = 0; s < 16; s++){
    const float* q = ps + (s * 64 + lane) * 3;
    double dx = xd - (double)q[0];
    double dy = yd - (double)q[1];
    double dz = zd - (double)q[2];
    dl[s] = dx * dx + dy * dy + dz * dz;
  }

  double dsel[3]; int isel[3];
  for (int p = 0; p < 3; p++){
    double dm = dl[0]; int sm = 0;
    for (int s = 1; s < 16; s++) if (dl[s] < dm){ dm = dl[s]; sm = s; }
    int im = sm * 64 + lane;
    for (int off = 1; off < 64; off <<= 1){
      double od = __shfl_xor(dm, off);
      int    oi = __shfl_xor(im, off);
      if (od < dm || (od == dm && oi < im)){ dm = od; im = oi; }  // stable: lowest index
    }
    dsel[p] = dm; isel[p] = im;
    if ((im & 63) == lane) dl[im >> 6] = 1e300;  // owner invalidates winner
  }

  double w0 = 1.0 / (dsel[0] + 1e-8);
  double w1 = 1.0 / (dsel[1] + 1e-8);
  double w2 = 1.0 / (dsel[2] + 1e-8);
  double wsum = w0 + w1 + w2;
  float f0 = (float)(w0 / wsum), f1 = (float)(w1 / wsum), f2 = (float)(w2 / wsum);

  const u16* r0 = Y1 + (size_t)(b * NN1 + isel[0]) * DIM;
  const u16* r1 = Y1 + (size_t)(b * NN1 + isel[1]) * DIM;
  const u16* r2 = Y1 + (size_t)(b * NN1 + isel[2]) * DIM;
  float* o = outF + (size_t)bid * DIM;

  int c0 = lane * 8;  // 8 contiguous channels per lane
  uint4 q0 = *(const uint4*)(r0 + c0);
  uint4 q1 = *(const uint4*)(r1 + c0);
  uint4 q2 = *(const uint4*)(r2 + c0);
  float4 ylo = *(const float4*)(o + c0);
  float4 yhi = *(const float4*)(o + c0 + 4);
  const u16* p0 = (const u16*)&q0;
  const u16* p1 = (const u16*)&q1;
  const u16* p2 = (const u16*)&q2;
  float yv[8] = { ylo.x, ylo.y, ylo.z, ylo.w, yhi.x, yhi.y, yhi.z, yhi.w };
  float res[8];
  for (int j = 0; j < 8; j++){
    int c = c0 + j;
    float a1 = coef[c],        b1 = coef[512 + c];
    float a2 = coef[1024 + c], b2 = coef[1536 + c];
    float v0 = fmaxf(a1 * bf2f(p0[j]) + b1, 0.0f);
    float v1 = fmaxf(a1 * bf2f(p1[j]) + b1, 0.0f);
    float v2 = fmaxf(a1 * bf2f(p2[j]) + b1, 0.0f);
    float vi = f0 * v0 + f1 * v1 + f2 * v2;
    float y2 = fmaxf(a2 * yv[j] + b2, 0.0f);
    res[j] = vi + y2;
  }
  *(float4*)(o + c0)     = make_float4(res[0], res[1], res[2], res[3]);
  *(float4*)(o + c0 + 4) = make_float4(res[4], res[5], res[6], res[7]);
}

extern "C" void kernel_launch(void* const* d_in, const int* in_sizes, int n_in,
                              void* d_out, int out_size, void* d_ws, size_t ws_size,
                              hipStream_t stream){
  const float* xyz1    = (const float*)d_in[0];
  const float* points1 = (const float*)d_in[1];
  const float* xyz2    = (const float*)d_in[2];
  const float* points2 = (const float*)d_in[3];
  const float* fc1_w   = (const float*)d_in[4];
  const float* fc1_b   = (const float*)d_in[5];
  const float* bn1_g   = (const float*)d_in[6];
  const float* bn1_b   = (const float*)d_in[7];
  const float* fc2_w   = (const float*)d_in[8];
  const float* fc2_b   = (const float*)d_in[9];
  const float* bn2_g   = (const float*)d_in[10];
  const float* bn2_b   = (const float*)d_in[11];

  // workspace (~17.5 MB): Y1 bf16 + bf16 weight transposes + stats/coef
  char* ws = (char*)d_ws;
  u16*   Y1    = (u16*)(ws);                       // 16384*512*2 = 16,777,216 B
  u16*   wT1   = (u16*)(ws + 16777216);            // 512*1024*2 = 1,048,576 B
  u16*   wT2   = (u16*)(ws + 17825792);            // 512*512*2  =   524,288 B
  float* stats = (float*)(ws + 18350080);          // 2048 f32
  float* coef  = (float*)(ws + 18358272);          // 2048 f32

  float* out  = (float*)d_out;
  float* outF = out + 196608;   // feats region [65536][512] f32; holds pre-BN Y2 mid-flight

  zero_stats<<<8, 256, 0, stream>>>(stats);
  transpose_w<<<(1024*512 + 255)/256, 256, 0, stream>>>(fc1_w, wT1, 1024, 512);
  transpose_w<<<( 512*512 + 255)/256, 256, 0, stream>>>(fc2_w, wT2,  512, 512);

  dim3 g1(4, 128);   // bn fast -> 4 blocks share each A tile in L2
  gemm_mfma<<<g1, 256, 0, stream>>>(points1, wT1, fc1_b, Y1,   M1, 1024, 0);
  dim3 g2(4, 512);
  gemm_mfma<<<g2, 256, 0, stream>>>(points2, wT2, fc2_b, outF, M2,  512, 1);

  colstats_bf16<<< 256, 256, 0, stream>>>(Y1,   stats,        stats + 512,  128);
  colstats_f32 <<<1024, 256, 0, stream>>>(outF, stats + 1024, stats + 1536, 128);
  bn_coeff<<<1, 512, 0, stream>>>(stats, bn1_g, bn1_b, bn2_g, bn2_b, coef);

  copy_xyz<<<192, 256, 0, stream>>>((const uint4*)xyz2, (uint4*)out);
  interp_final<<<65536, 64, 0, stream>>>(xyz1, xyz2, Y1, coef, outF);
}